// Round 1
// baseline (353.580 us; speedup 1.0000x reference)
//
#include <hip/hip_runtime.h>
#include <cstdint>
#include <cstddef>

// ExpertGather: Y[b,e,k,j] = sum_i X[b, ind[b,e,k], i] * W[e,i,j]
// B=4 T=4096 I=1024 E=16 K=512 J=1024
//
// Strategy: fp16 MFMA grouped GEMM (threshold 6.7e-2 permits 16-bit compute).
//  - pre-pass converts X -> fp16 and W -> W^T fp16 in d_ws (64 MiB needed);
//    fallback path does inline convert/transpose if ws_size is too small.
//  - GEMM: 128x128 tile / block, BK=64, mfma_f32_16x16x32_f16, gather via LDS row table.

typedef float    floatx4 __attribute__((ext_vector_type(4)));
typedef int      intx4   __attribute__((ext_vector_type(4)));
typedef _Float16 half8   __attribute__((ext_vector_type(8)));
typedef _Float16 half4v  __attribute__((ext_vector_type(4)));

constexpr int Bc = 4, Tc = 4096, Ic = 1024, Ec = 16, Kc = 512, Jc = 1024;
constexpr int BM = 128, BN = 128, BK = 64, NT = 256;
constexpr int AS = BK + 8;  // LDS row stride in halves: 72*2=144 B (16B-aligned, banks rotate by 4/row)

// ---------- pre-pass: X fp32 -> fp16 ----------
__global__ void cvt_x_kernel(const float* __restrict__ X, _Float16* __restrict__ Xh, int n4) {
  int i = blockIdx.x * blockDim.x + threadIdx.x;
  int stride = gridDim.x * blockDim.x;
  for (; i < n4; i += stride) {
    floatx4 v = ((const floatx4*)X)[i];
    half4v h;
    h.x = (_Float16)v.x; h.y = (_Float16)v.y; h.z = (_Float16)v.z; h.w = (_Float16)v.w;
    ((half4v*)Xh)[i] = h;
  }
}

// ---------- pre-pass: W [E][I][J] fp32 -> WT [E][J][I] fp16 (transpose per expert) ----------
__global__ void cvt_w_kernel(const float* __restrict__ W, _Float16* __restrict__ WT) {
  __shared__ float tile[64][65];
  int bid = blockIdx.x;
  int e  = bid >> 8;               // 16 experts
  int i0 = ((bid >> 4) & 15) * 64; // 16 i-tiles
  int j0 = (bid & 15) * 64;        // 16 j-tiles
  int tid = threadIdx.x;
  int r  = tid >> 4;   // 0..15
  int c4 = tid & 15;   // 0..15
  const float* src = W + ((size_t)e << 20) + (size_t)i0 * Jc + j0;
#pragma unroll
  for (int s = 0; s < 4; s++) {
    int rr = r + s * 16;
    floatx4 v = *(const floatx4*)(src + (size_t)rr * Jc + c4 * 4);
    tile[rr][c4 * 4 + 0] = v.x; tile[rr][c4 * 4 + 1] = v.y;
    tile[rr][c4 * 4 + 2] = v.z; tile[rr][c4 * 4 + 3] = v.w;
  }
  __syncthreads();
  int jj = tid >> 2;   // 0..63  (output row j0+jj)
  int ig = tid & 3;    // 0..3   (16 i's each)
  half8 hv0, hv1;
#pragma unroll
  for (int q = 0; q < 8; q++) hv0[q] = (_Float16)tile[ig * 16 + q][jj];
#pragma unroll
  for (int q = 0; q < 8; q++) hv1[q] = (_Float16)tile[ig * 16 + 8 + q][jj];
  _Float16* dst = WT + ((size_t)e << 20) + (size_t)(j0 + jj) * Ic + i0 + ig * 16;
  ((half8*)dst)[0] = hv0;
  ((half8*)dst)[1] = hv1;
}

// ---------- main grouped GEMM ----------
// Fragment layouts (guide §3, m89/m120 verified):
//   A: m = lane&15, k = (lane>>4)*8 + j   (8 contiguous k per lane -> ds_read_b128)
//   B: n = lane&15, k = (lane>>4)*8 + j
//   C/D: col = lane&15, row = (lane>>4)*4 + reg
template <bool PRE>
__global__ __launch_bounds__(NT, 2) void gemm_kernel(
    const float* __restrict__ X, const int* __restrict__ ind32,
    const float* __restrict__ W,
    const _Float16* __restrict__ Xh, const _Float16* __restrict__ WT,
    float* __restrict__ Y) {
  __shared__ _Float16 As[BM * AS];
  __shared__ _Float16 Bs[BN * AS];
  __shared__ int rowid[BM];
  __shared__ int is64_s;

  const int tid = threadIdx.x;
  const int bid = blockIdx.x;
  constexpr int NTILE = Jc / BN;  // 8
  constexpr int MTILE = Kc / BM;  // 4
  const int tileid = bid % (NTILE * MTILE);
  const int be = bid / (NTILE * MTILE);  // 0..63
  const int mt = tileid / NTILE;
  const int nt = tileid % NTILE;
  const int b = be / Ec, e = be % Ec;
  const int k0 = mt * BM;
  const int j0 = nt * BN;

  // ---- index dtype probe: reference declares int64 but harness doc says int32.
  // If stored as int64 (LE), every odd 32-bit word of the first 128 entries is 0.
  // For int32 data those words are random indices in [0,4096) -> P(all zero) ~ 0.
  if (tid == 0) {
    int orv = 0;
    for (int q = 1; q < 256; q += 2) orv |= ind32[q];
    is64_s = (orv == 0) ? 1 : 0;
  }
  __syncthreads();
  if (tid < BM) {
    int idx = be * Kc + k0 + tid;
    rowid[tid] = is64_s ? ind32[2 * idx] : ind32[idx];
  }
  __syncthreads();

  const int lane = tid & 63;
  const int wave = tid >> 6;
  const int wm = (wave >> 1) * 64;
  const int wn = (wave & 1) * 64;
  const int quad = lane >> 4;
  const int tr = lane & 15;

  floatx4 acc[4][4];
#pragma unroll
  for (int mi = 0; mi < 4; mi++)
#pragma unroll
    for (int ni = 0; ni < 4; ni++) acc[mi][ni] = {0.f, 0.f, 0.f, 0.f};

  for (int kk0 = 0; kk0 < Ic; kk0 += BK) {
    if constexpr (PRE) {
      // A: gathered fp16 rows, 16B chunks
#pragma unroll
      for (int it = 0; it < 4; it++) {
        int c = tid + it * NT;           // 0..1023
        int row = c >> 3, kc = c & 7;    // 128 rows x 8 chunks
        const _Float16* src = Xh + ((size_t)b * Tc + rowid[row]) * Ic + kk0 + kc * 8;
        *(intx4*)&As[row * AS + kc * 8] = *(const intx4*)src;
      }
      // B: W^T fp16 rows (j-major, i-contiguous)
#pragma unroll
      for (int it = 0; it < 4; it++) {
        int c = tid + it * NT;
        int row = c >> 3, kc = c & 7;
        const _Float16* src = WT + ((size_t)e * Jc + j0 + row) * Ic + kk0 + kc * 8;
        *(intx4*)&Bs[row * AS + kc * 8] = *(const intx4*)src;
      }
    } else {
      // A: fp32 gather + convert
#pragma unroll
      for (int it = 0; it < 4; it++) {
        int c = tid + it * NT;
        int row = c >> 3, kc = c & 7;
        const float* src = X + ((size_t)b * Tc + rowid[row]) * Ic + kk0 + kc * 8;
        floatx4 v0 = *(const floatx4*)src;
        floatx4 v1 = *(const floatx4*)(src + 4);
        half8 h;
        h[0] = (_Float16)v0.x; h[1] = (_Float16)v0.y; h[2] = (_Float16)v0.z; h[3] = (_Float16)v0.w;
        h[4] = (_Float16)v1.x; h[5] = (_Float16)v1.y; h[6] = (_Float16)v1.z; h[7] = (_Float16)v1.w;
        *(half8*)&As[row * AS + kc * 8] = h;
      }
      // B: strided fp32 reads of W (coalesced across lanes), inline transpose
      {
        int n = tid & 127;
        int kh = tid >> 7;  // 0..1 -> k halves of 32
        const float* src = W + ((size_t)e * Ic + kk0 + kh * 32) * Jc + j0 + n;
        _Float16 hv[32];
#pragma unroll
        for (int q = 0; q < 32; q++) hv[q] = (_Float16)src[(size_t)q * Jc];
#pragma unroll
        for (int g = 0; g < 4; g++) {
          half8 hh;
#pragma unroll
          for (int q = 0; q < 8; q++) hh[q] = hv[g * 8 + q];
          *(half8*)&Bs[n * AS + kh * 32 + g * 8] = hh;
        }
      }
    }
    __syncthreads();

#pragma unroll
    for (int ks = 0; ks < 2; ks++) {
      const int kk = ks * 32;
      half8 af[4], bf[4];
#pragma unroll
      for (int mi = 0; mi < 4; mi++)
        af[mi] = *(const half8*)&As[(wm + mi * 16 + tr) * AS + kk + quad * 8];
#pragma unroll
      for (int ni = 0; ni < 4; ni++)
        bf[ni] = *(const half8*)&Bs[(wn + ni * 16 + tr) * AS + kk + quad * 8];
#pragma unroll
      for (int mi = 0; mi < 4; mi++)
#pragma unroll
        for (int ni = 0; ni < 4; ni++)
          acc[mi][ni] = __builtin_amdgcn_mfma_f32_16x16x32_f16(af[mi], bf[ni], acc[mi][ni], 0, 0, 0);
    }
    __syncthreads();
  }

  // epilogue: C/D layout col=lane&15, row=quad*4+reg
  float* Yb = Y + (size_t)be * Kc * Jc;
#pragma unroll
  for (int mi = 0; mi < 4; mi++) {
#pragma unroll
    for (int ni = 0; ni < 4; ni++) {
      const int col = j0 + wn + ni * 16 + tr;
#pragma unroll
      for (int r = 0; r < 4; r++) {
        const int row = k0 + wm + mi * 16 + quad * 4 + r;
        Yb[(size_t)row * Jc + col] = acc[mi][ni][r];
      }
    }
  }
}

extern "C" void kernel_launch(void* const* d_in, const int* in_sizes, int n_in,
                              void* d_out, int out_size, void* d_ws, size_t ws_size,
                              hipStream_t stream) {
  const float* X = (const float*)d_in[0];
  const int* ind = (const int*)d_in[1];
  const float* W = (const float*)d_in[2];
  float* Y = (float*)d_out;

  const size_t nx = (size_t)Bc * Tc * Ic;            // 16.78M halves
  const size_t nw = (size_t)Ec * Ic * Jc;            // 16.78M halves
  const size_t need = (nx + nw) * sizeof(_Float16);  // 64 MiB
  const int gemm_grid = Bc * Ec * (Kc / BM) * (Jc / BN);  // 2048

  if (ws_size >= need) {
    _Float16* Xh = (_Float16*)d_ws;
    _Float16* WT = Xh + nx;
    cvt_x_kernel<<<4096, NT, 0, stream>>>(X, Xh, (int)(nx / 4));
    cvt_w_kernel<<<Ec * 256, NT, 0, stream>>>(W, WT);
    gemm_kernel<true><<<gemm_grid, NT, 0, stream>>>(X, ind, W, Xh, WT, Y);
  } else {
    gemm_kernel<false><<<gemm_grid, NT, 0, stream>>>(X, ind, W, nullptr, nullptr, Y);
  }
}